// Round 1
// baseline (272.460 us; speedup 1.0000x reference)
//
#include <hip/hip_runtime.h>
#include <hip/hip_bf16.h>
#include <stdint.h>

#define B_  4
#define S_  2048
#define D_  1024
#define H_  1024
#define BS_ (B_*S_)    // 8192
#define N3H (3*H_)     // 3072

typedef __bf16 bf16x8 __attribute__((ext_vector_type(8)));
typedef float  f32x4  __attribute__((ext_vector_type(4)));
typedef unsigned short u16x8 __attribute__((ext_vector_type(8)));

__device__ __forceinline__ unsigned short f2bf(float x) {
    unsigned u = __float_as_uint(x);
    return (unsigned short)((u + 0x7FFFu + ((u >> 16) & 1u)) >> 16);  // RNE
}
__device__ __forceinline__ float bf2f(unsigned short h) {
    return __uint_as_float(((unsigned)h) << 16);
}

__device__ __forceinline__ void gload_lds16(const void* g, void* l) {
    __builtin_amdgcn_global_load_lds(
        (const __attribute__((address_space(1))) void*)g,
        (__attribute__((address_space(3))) void*)l, 16, 0, 0);
}

// ---------------------------------------------------------------------------
// Generic bt-GEMM: C[M,N] = A[M,K] @ B[N,K]^T   (all bf16 in, f32 accum)
// 128x128 tile, BK=32, 4 waves (2x2), 4x4 16x16x32 frags per wave (m97 structure)
// EPI 0: QKV split  -> out0/out1/out2 bf16 [*,1024], +bias
// EPI 1: bf16 out0, * scale  (scores / ctx)
// EPI 3: f32  out0, +bias    (final)
// ---------------------------------------------------------------------------
template<int EPI>
__global__ __launch_bounds__(256) void gemm_bt(
    const unsigned short* __restrict__ A,
    const unsigned short* __restrict__ Bm,
    int M, int N, int K,
    long long sAz, long long sBz, long long sOz,
    void* __restrict__ out0, void* __restrict__ out1, void* __restrict__ out2,
    const float* __restrict__ bias, float scale)
{
    __shared__ unsigned short As[128 * 32];
    __shared__ unsigned short Bs[128 * 32];

    const unsigned short* Ab = A  + blockIdx.z * sAz;
    const unsigned short* Bb = Bm + blockIdx.z * sBz;
    const int rowBase = blockIdx.y * 128;
    const int colBase = blockIdx.x * 128;
    const int tid = threadIdx.x;
    const int w = tid >> 6, l = tid & 63;
    const int wr = w >> 1, wc = w & 1;

    f32x4 acc[4][4];
#pragma unroll
    for (int m = 0; m < 4; m++)
#pragma unroll
        for (int n = 0; n < 4; n++) acc[m][n] = (f32x4){0.f, 0.f, 0.f, 0.f};

    // staging: thread t covers 16B chunk t -> LDS row t/4, col (t%4)*8
    const int sr  = tid >> 2;
    const int sc8 = (tid & 3) * 8;
    const unsigned short* gA0 = Ab + (long long)(rowBase + sr) * K + sc8;
    const unsigned short* gA1 = gA0 + (long long)64 * K;
    const unsigned short* gB0 = Bb + (long long)(colBase + sr) * K + sc8;
    const unsigned short* gB1 = gB0 + (long long)64 * K;
    char* lA0 = (char*)As + w * 1024;
    char* lA1 = (char*)As + 4096 + w * 1024;
    char* lB0 = (char*)Bs + w * 1024;
    char* lB1 = (char*)Bs + 4096 + w * 1024;

    const int fr = l & 15, fq = l >> 4;
    const int aoff = (wr * 64 + fr) * 32 + fq * 8;   // elem offset, m=0
    const int boff = (wc * 64 + fr) * 32 + fq * 8;   // elem offset, n=0

    for (int kt = 0; kt < K; kt += 32) {
        gload_lds16(gA0 + kt, lA0);
        gload_lds16(gA1 + kt, lA1);
        gload_lds16(gB0 + kt, lB0);
        gload_lds16(gB1 + kt, lB1);
        __syncthreads();   // drains vmcnt before barrier (compiler-emitted)

        bf16x8 af[4], bfv[4];
#pragma unroll
        for (int m = 0; m < 4; m++)
            af[m] = *reinterpret_cast<const bf16x8*>(&As[aoff + m * 16 * 32]);
#pragma unroll
        for (int n = 0; n < 4; n++)
            bfv[n] = *reinterpret_cast<const bf16x8*>(&Bs[boff + n * 16 * 32]);
#pragma unroll
        for (int m = 0; m < 4; m++)
#pragma unroll
            for (int n = 0; n < 4; n++)
                acc[m][n] = __builtin_amdgcn_mfma_f32_16x16x32_bf16(
                    af[m], bfv[n], acc[m][n], 0, 0, 0);
        __syncthreads();
    }

    // epilogue: row = crow0 + m*16 + j, col = ccol0 + n*16  (m89-verified C/D map)
    const int crow0 = rowBase + wr * 64 + fq * 4;
    const int ccol0 = colBase + wc * 64 + fr;

#pragma unroll
    for (int n = 0; n < 4; n++) {
        const int col = ccol0 + n * 16;
        if constexpr (EPI == 0) {
            const float bv = bias[col];
            const int seg = col >> 10, scn = col & 1023;
            unsigned short* dst =
                (unsigned short*)(seg == 0 ? out0 : (seg == 1 ? out1 : out2));
#pragma unroll
            for (int m = 0; m < 4; m++) {
                const int r0 = crow0 + m * 16;
#pragma unroll
                for (int j = 0; j < 4; j++)
                    dst[(long long)(r0 + j) * 1024 + scn] = f2bf(acc[m][n][j] + bv);
            }
        } else if constexpr (EPI == 1) {
            unsigned short* dst = (unsigned short*)out0 + blockIdx.z * sOz;
#pragma unroll
            for (int m = 0; m < 4; m++) {
                const int r0 = crow0 + m * 16;
#pragma unroll
                for (int j = 0; j < 4; j++)
                    dst[(long long)(r0 + j) * N + col] = f2bf(acc[m][n][j] * scale);
            }
        } else {
            float* dst = (float*)out0;
            const float bv = bias[col];
#pragma unroll
            for (int m = 0; m < 4; m++) {
                const int r0 = crow0 + m * 16;
#pragma unroll
                for (int j = 0; j < 4; j++)
                    dst[(long long)(r0 + j) * N + col] = acc[m][n][j] + bv;
            }
        }
    }
}

// f32 -> bf16 elementwise (8/thread, vectorized)
__global__ __launch_bounds__(256) void conv_f32_bf16(
    const float* __restrict__ in, unsigned short* __restrict__ out, int n8)
{
    for (int i = blockIdx.x * blockDim.x + threadIdx.x; i < n8;
         i += gridDim.x * blockDim.x) {
        const float4 a = ((const float4*)in)[2 * i];
        const float4 b = ((const float4*)in)[2 * i + 1];
        u16x8 o;
        o[0] = f2bf(a.x); o[1] = f2bf(a.y); o[2] = f2bf(a.z); o[3] = f2bf(a.w);
        o[4] = f2bf(b.x); o[5] = f2bf(b.y); o[6] = f2bf(b.z); o[7] = f2bf(b.w);
        ((u16x8*)out)[i] = o;
    }
}

// out[cols][rows] (bf16) = transpose(in[rows][cols] f32)
__global__ __launch_bounds__(256) void tconv_f32_bf16(
    const float* __restrict__ in, unsigned short* __restrict__ out,
    int rows, int cols)
{
    __shared__ float t[32][33];
    const int c0 = blockIdx.x * 32, r0 = blockIdx.y * 32;
    const int tx = threadIdx.x & 31, ty = threadIdx.x >> 5;
#pragma unroll
    for (int i = 0; i < 4; i++)
        t[ty + 8 * i][tx] = in[(long long)(r0 + ty + 8 * i) * cols + c0 + tx];
    __syncthreads();
#pragma unroll
    for (int i = 0; i < 4; i++)
        out[(long long)(c0 + ty + 8 * i) * rows + r0 + tx] = f2bf(t[tx][ty + 8 * i]);
}

// bf16 transpose, batched via grid.z
__global__ __launch_bounds__(256) void t_bf16(
    const unsigned short* __restrict__ in, unsigned short* __restrict__ out,
    int rows, int cols, long long sIz, long long sOz)
{
    __shared__ unsigned short t[32][33];
    in  += blockIdx.z * sIz;
    out += blockIdx.z * sOz;
    const int c0 = blockIdx.x * 32, r0 = blockIdx.y * 32;
    const int tx = threadIdx.x & 31, ty = threadIdx.x >> 5;
#pragma unroll
    for (int i = 0; i < 4; i++)
        t[ty + 8 * i][tx] = in[(long long)(r0 + ty + 8 * i) * cols + c0 + tx];
    __syncthreads();
#pragma unroll
    for (int i = 0; i < 4; i++)
        out[(long long)(c0 + ty + 8 * i) * rows + r0 + tx] = t[tx][ty + 8 * i];
}

// in-place row softmax over S_=2048 bf16 logits; one block (256 thr) per row
__global__ __launch_bounds__(256) void softmax_rows(unsigned short* __restrict__ sc)
{
    const long long row = blockIdx.x;
    unsigned short* p = sc + row * S_;
    const int tid = threadIdx.x, w = tid >> 6, l = tid & 63;

    u16x8 v = *reinterpret_cast<const u16x8*>(&p[tid * 8]);
    float f[8];
#pragma unroll
    for (int i = 0; i < 8; i++) f[i] = bf2f(v[i]);

    float m = f[0];
#pragma unroll
    for (int i = 1; i < 8; i++) m = fmaxf(m, f[i]);
    for (int o = 32; o; o >>= 1) m = fmaxf(m, __shfl_xor(m, o));
    __shared__ float red[8];
    if (l == 0) red[w] = m;
    __syncthreads();
    m = fmaxf(fmaxf(red[0], red[1]), fmaxf(red[2], red[3]));

    float s = 0.f;
#pragma unroll
    for (int i = 0; i < 8; i++) { f[i] = __expf(f[i] - m); s += f[i]; }
    for (int o = 32; o; o >>= 1) s += __shfl_xor(s, o);
    if (l == 0) red[4 + w] = s;
    __syncthreads();
    s = red[4] + red[5] + red[6] + red[7];

    const float inv = 1.0f / s;
    u16x8 o8;
#pragma unroll
    for (int i = 0; i < 8; i++) o8[i] = f2bf(f[i] * inv);
    *reinterpret_cast<u16x8*>(&p[tid * 8]) = o8;
}

extern "C" void kernel_launch(void* const* d_in, const int* in_sizes, int n_in,
                              void* d_out, int out_size, void* d_ws, size_t ws_size,
                              hipStream_t stream)
{
    (void)in_sizes; (void)n_in; (void)out_size; (void)ws_size;
    const float* x  = (const float*)d_in[0];
    const float* W1 = (const float*)d_in[1];
    const float* b1 = (const float*)d_in[2];
    const float* W2 = (const float*)d_in[3];
    const float* b2 = (const float*)d_in[4];
    float* out = (float*)d_out;

    char* ws = (char*)d_ws;
    size_t off = 0;
    auto alloc = [&](size_t bytes) {
        void* p = ws + off;
        off += (bytes + 255) & ~(size_t)255;
        return p;
    };
    unsigned short* xbf = (unsigned short*)alloc((size_t)BS_ * D_ * 2);
    unsigned short* w1t = (unsigned short*)alloc((size_t)N3H * D_ * 2);
    unsigned short* w2t = (unsigned short*)alloc((size_t)H_ * H_ * 2);
    unsigned short* q   = (unsigned short*)alloc((size_t)BS_ * H_ * 2);
    unsigned short* k   = (unsigned short*)alloc((size_t)BS_ * H_ * 2);
    unsigned short* v   = (unsigned short*)alloc((size_t)BS_ * H_ * 2);
    unsigned short* vt  = (unsigned short*)alloc((size_t)BS_ * H_ * 2);
    unsigned short* sc  = (unsigned short*)alloc((size_t)B_ * S_ * S_ * 2);
    unsigned short* ctx = v;  // alias: v is dead after transpose, before PV writes

    const float scale = 0.022097086912079608f;  // (2*D)^-0.5 = 1/sqrt(2048)

    conv_f32_bf16<<<dim3(2048), dim3(256), 0, stream>>>(x, xbf, BS_ * D_ / 8);
    tconv_f32_bf16<<<dim3(N3H / 32, D_ / 32), dim3(256), 0, stream>>>(W1, w1t, D_, N3H);
    tconv_f32_bf16<<<dim3(H_ / 32, H_ / 32), dim3(256), 0, stream>>>(W2, w2t, H_, H_);

    // QKV: [8192,3072] = xbf @ w1t^T, split into q/k/v, +b1
    gemm_bt<0><<<dim3(N3H / 128, BS_ / 128, 1), dim3(256), 0, stream>>>(
        xbf, w1t, BS_, N3H, D_, 0LL, 0LL, 0LL, q, k, v, b1, 1.0f);

    // vt[b][h][s] = v[b][s][h]
    t_bf16<<<dim3(H_ / 32, S_ / 32, B_), dim3(256), 0, stream>>>(
        v, vt, S_, H_, (long long)S_ * H_, (long long)S_ * H_);

    // scores[b] = (q[b] @ k[b]^T) * scale   [2048,2048] bf16
    gemm_bt<1><<<dim3(S_ / 128, S_ / 128, B_), dim3(256), 0, stream>>>(
        q, k, S_, S_, H_, (long long)S_ * H_, (long long)S_ * H_, (long long)S_ * S_,
        sc, nullptr, nullptr, nullptr, scale);

    softmax_rows<<<dim3(BS_), dim3(256), 0, stream>>>(sc);

    // ctx[b] = P[b] @ vt[b]^T   [2048,1024] bf16
    gemm_bt<1><<<dim3(H_ / 128, S_ / 128, B_), dim3(256), 0, stream>>>(
        sc, vt, S_, H_, S_, (long long)S_ * S_, (long long)H_ * S_, (long long)S_ * H_,
        ctx, nullptr, nullptr, nullptr, 1.0f);

    // out = ctx @ w2t^T + b2   [8192,1024] f32
    gemm_bt<3><<<dim3(H_ / 128, BS_ / 128, 1), dim3(256), 0, stream>>>(
        ctx, w2t, BS_, H_, H_, 0LL, 0LL, 0LL, out, nullptr, nullptr, b2, 1.0f);
}

// Round 2
// 240.022 us; speedup vs baseline: 1.1351x; 1.1351x over previous
//
#include <hip/hip_runtime.h>
#include <hip/hip_bf16.h>
#include <stdint.h>

#define B_  4
#define S_  2048
#define D_  1024
#define H_  1024
#define BS_ (B_*S_)    // 8192
#define N3H (3*H_)     // 3072

typedef __bf16 bf16x8 __attribute__((ext_vector_type(8)));
typedef float  f32x4  __attribute__((ext_vector_type(4)));
typedef unsigned short u16x8 __attribute__((ext_vector_type(8)));

__device__ __forceinline__ unsigned short f2bf(float x) {
    unsigned u = __float_as_uint(x);
    return (unsigned short)((u + 0x7FFFu + ((u >> 16) & 1u)) >> 16);  // RNE
}
__device__ __forceinline__ float bf2f(unsigned short h) {
    return __uint_as_float(((unsigned)h) << 16);
}

__device__ __forceinline__ void gload_lds16(const void* g, void* l) {
    __builtin_amdgcn_global_load_lds(
        (const __attribute__((address_space(1))) void*)g,
        (__attribute__((address_space(3))) void*)l, 16, 0, 0);
}

// ---------------------------------------------------------------------------
// 256x256 8-phase bt-GEMM (T2 st_16x32 swizzle + T3/T4 counted vmcnt + T5).
// C[M,N] = A[M,K] @ B[N,K]^T, bf16 in, f32 accum. BK=64, 8 waves (2Mx4N),
// 512 threads, 128 KiB LDS (2 dbuf x (A 32K + B 32K)), half-tile = 128x64.
// LDS element (r,c) of a half-tile lives at byte:
//   st=(r>>4)*2+(c>>5); off=st*1024 + (((r&15)*64+(c&31)*2) ^ ((r&8)?32:0))
// Staged linearly by global_load_lds (thread t -> byte t*16 (+8192 for j=1)),
// with the SOURCE address inverse-swizzled (rule #21).
// Steady-state stage slots (iter i = tiles 2i,2i+1):
//  ph1:buf1.B0<-t1 ph2:buf1.B1<-t1 ph3:buf0.A0<-t2 ph4:buf0.A1<-t2 +vmcnt(4)
//  ph5:buf0.B0<-t2 ph6:buf0.B1<-t2 ph7:buf1.A0<-t3 ph8:buf1.A1<-t3 +vmcnt(4)
// A-half reads finish end-ph2 (quadrant order m-lo,m-hi,n-hi), B end-ph3.
// ---------------------------------------------------------------------------
template<int EPI>
__global__ __launch_bounds__(512, 2) void gemm256(
    const unsigned short* __restrict__ A,
    const unsigned short* __restrict__ Bm,
    int M, int N, int K,
    long long sAz, long long sBz, long long sOz,
    void* __restrict__ out0, void* __restrict__ out1, void* __restrict__ out2,
    const float* __restrict__ bias, float scale)
{
    __shared__ __align__(16) char lds[131072];
    (void)M;

    const unsigned short* Ab = A  + blockIdx.z * sAz;
    const unsigned short* Bb = Bm + blockIdx.z * sBz;
    const int rowBase = blockIdx.y * 256;
    const int colBase = blockIdx.x * 256;
    const int tid = threadIdx.x;
    const int w = tid >> 6, l = tid & 63;
    const int wr = w >> 2, wc = w & 3;          // 2M x 4N waves
    const int fr = l & 15, fq = l >> 4;

    // staging source decode: LDS linear offset o = j*8192 + tid*16 within a
    // half-tile; invert subtile+swizzle to get (row, col) this thread fetches
    int sr[2], scl[2];
#pragma unroll
    for (int j = 0; j < 2; j++) {
        int o  = j * 8192 + tid * 16;
        int st = o >> 10;
        int wi = o & 1023;
        wi ^= ((wi >> 9) & 1) << 5;             // involution
        sr[j]  = (st >> 1) * 16 + (wi >> 6);
        scl[j] = (st & 1) * 32 + ((wi & 63) >> 1);
    }

    auto STAGE = [&](int buf, int which /*0=A0,1=A1,2=B0,3=B1*/, int tile) {
        const unsigned short* mat = (which < 2) ? Ab : Bb;
        const int rt0 = ((which < 2) ? rowBase : colBase) + (which & 1) * 128;
        char* dst = lds + buf * 65536 + (which >> 1) * 32768
                        + (which & 1) * 16384 + w * 1024;
        const int k0 = tile * 64;
#pragma unroll
        for (int j = 0; j < 2; j++) {
            const unsigned short* src =
                mat + (long long)(rt0 + sr[j]) * K + k0 + scl[j];
            gload_lds16(src, dst + j * 8192);
        }
    };

    // fragment read bases (swizzled)
    const int abase = (fr * 64 + fq * 16) ^ ((fr & 8) << 2);
    const char* Ah[2] = { lds + wr * 16384, lds + 65536 + wr * 16384 };
    const char* Bh[2] = { lds + 32768 + (wc >> 1) * 16384,
                          lds + 98304 + (wc >> 1) * 16384 };
    const int bn0 = (wc & 1) * 8192;   // ((wc&1)*4) * 2048

#define LA(b, m, kk) (*(const bf16x8*)(Ah[b] + (m)*2048 + (kk)*1024 + abase))
#define LB(b, n, kk) (*(const bf16x8*)(Bh[b] + bn0 + (n)*2048 + (kk)*1024 + abase))
#define BAR __builtin_amdgcn_s_barrier()
#define DS_FENCE do { asm volatile("s_waitcnt lgkmcnt(0)" ::: "memory"); \
                      __builtin_amdgcn_sched_barrier(0); } while (0)
#define MFMA16(AF, BF, MOFF, NOFF) do { \
    __builtin_amdgcn_s_setprio(1); \
    _Pragma("unroll") for (int m_ = 0; m_ < 4; m_++) \
    _Pragma("unroll") for (int n_ = 0; n_ < 2; n_++) \
    _Pragma("unroll") for (int k_ = 0; k_ < 2; k_++) \
        acc[(MOFF)+m_][(NOFF)+n_] = __builtin_amdgcn_mfma_f32_16x16x32_bf16( \
            AF[m_][k_], BF[n_][k_], acc[(MOFF)+m_][(NOFF)+n_], 0, 0, 0); \
    __builtin_amdgcn_s_setprio(0); } while (0)

    f32x4 acc[8][4];
#pragma unroll
    for (int m = 0; m < 8; m++)
#pragma unroll
        for (int n = 0; n < 4; n++) acc[m][n] = (f32x4){0.f, 0.f, 0.f, 0.f};

    const int NT = K >> 6;

    // prologue: tile0 fully + tile1 A-halves; wait tile0 (oldest 8 of 12 loads)
    STAGE(0, 0, 0); STAGE(0, 1, 0); STAGE(0, 2, 0); STAGE(0, 3, 0);
    STAGE(1, 0, 1); STAGE(1, 1, 1);
    asm volatile("s_waitcnt vmcnt(4)" ::: "memory");
    BAR;
    __builtin_amdgcn_sched_barrier(0);

    bf16x8 afA[4][2], afB[4][2], bfA[2][2], bfB[2][2];

    for (int i = 0; i < NT / 2; i++) {
        const int t1 = 2 * i + 1;
        int t2 = 2 * i + 2; if (t2 >= NT) t2 -= NT;
        int t3 = 2 * i + 3; if (t3 >= NT) t3 -= NT;

        // ---- tile 2i in buf0 ----
        // ph1: A m0-3 + B n0-1
#pragma unroll
        for (int m = 0; m < 4; m++) { afA[m][0] = LA(0, m, 0); afA[m][1] = LA(0, m, 1); }
#pragma unroll
        for (int n = 0; n < 2; n++) { bfA[n][0] = LB(0, n, 0); bfA[n][1] = LB(0, n, 1); }
        STAGE(1, 2, t1);
        BAR; DS_FENCE;
        MFMA16(afA, bfA, 0, 0);
        BAR;
        // ph2: A m4-7
#pragma unroll
        for (int m = 0; m < 4; m++) { afB[m][0] = LA(0, 4 + m, 0); afB[m][1] = LA(0, 4 + m, 1); }
        STAGE(1, 3, t1);
        BAR; DS_FENCE;
        MFMA16(afB, bfA, 4, 0);
        BAR;
        // ph3: B n2-3
#pragma unroll
        for (int n = 0; n < 2; n++) { bfB[n][0] = LB(0, 2 + n, 0); bfB[n][1] = LB(0, 2 + n, 1); }
        STAGE(0, 0, t2);
        BAR; DS_FENCE;
        MFMA16(afA, bfB, 0, 2);
        BAR;
        // ph4
        STAGE(0, 1, t2);
        BAR;
        MFMA16(afB, bfB, 4, 2);
        asm volatile("s_waitcnt vmcnt(4)" ::: "memory");
        BAR;
        __builtin_amdgcn_sched_barrier(0);

        // ---- tile 2i+1 in buf1 ----
        // ph5
#pragma unroll
        for (int m = 0; m < 4; m++) { afA[m][0] = LA(1, m, 0); afA[m][1] = LA(1, m, 1); }
#pragma unroll
        for (int n = 0; n < 2; n++) { bfA[n][0] = LB(1, n, 0); bfA[n][1] = LB(1, n, 1); }
        STAGE(0, 2, t2);
        BAR; DS_FENCE;
        MFMA16(afA, bfA, 0, 0);
        BAR;
        // ph6
#pragma unroll
        for (int m = 0; m < 4; m++) { afB[m][0] = LA(1, 4 + m, 0); afB[m][1] = LA(1, 4 + m, 1); }
        STAGE(0, 3, t2);
        BAR; DS_FENCE;
        MFMA16(afB, bfA, 4, 0);
        BAR;
        // ph7
#pragma unroll
        for (int n = 0; n < 2; n++) { bfB[n][0] = LB(1, 2 + n, 0); bfB[n][1] = LB(1, 2 + n, 1); }
        STAGE(1, 0, t3);
        BAR; DS_FENCE;
        MFMA16(afA, bfB, 0, 2);
        BAR;
        // ph8
        STAGE(1, 1, t3);
        BAR;
        MFMA16(afB, bfB, 4, 2);
        asm volatile("s_waitcnt vmcnt(4)" ::: "memory");
        BAR;
        __builtin_amdgcn_sched_barrier(0);
    }

    asm volatile("s_waitcnt vmcnt(0) lgkmcnt(0)" ::: "memory");

    // epilogue: row = rowBase + wr*128 + m*16 + fq*4 + j; col = colBase + wc*64 + n*16 + fr
    const int crow0 = rowBase + wr * 128 + fq * 4;
    const int ccol0 = colBase + wc * 64 + fr;

#pragma unroll
    for (int n = 0; n < 4; n++) {
        const int col = ccol0 + n * 16;
        if constexpr (EPI == 0) {
            const float bv = bias[col];
            const int seg = col >> 10, scn = col & 1023;
            unsigned short* dst =
                (unsigned short*)(seg == 0 ? out0 : (seg == 1 ? out1 : out2));
#pragma unroll
            for (int m = 0; m < 8; m++) {
                const int r0 = crow0 + m * 16;
#pragma unroll
                for (int j = 0; j < 4; j++)
                    dst[(long long)(r0 + j) * 1024 + scn] = f2bf(acc[m][n][j] + bv);
            }
        } else if constexpr (EPI == 1) {
            unsigned short* dst = (unsigned short*)out0 + blockIdx.z * sOz;
#pragma unroll
            for (int m = 0; m < 8; m++) {
                const int r0 = crow0 + m * 16;
#pragma unroll
                for (int j = 0; j < 4; j++)
                    dst[(long long)(r0 + j) * N + col] = f2bf(acc[m][n][j] * scale);
            }
        } else {
            float* dst = (float*)out0;
            const float bv = bias[col];
#pragma unroll
            for (int m = 0; m < 8; m++) {
                const int r0 = crow0 + m * 16;
#pragma unroll
                for (int j = 0; j < 4; j++)
                    dst[(long long)(r0 + j) * N + col] = acc[m][n][j] + bv;
            }
        }
    }
#undef LA
#undef LB
#undef BAR
#undef DS_FENCE
#undef MFMA16
}

// f32 -> bf16 elementwise (8/thread, vectorized)
__global__ __launch_bounds__(256) void conv_f32_bf16(
    const float* __restrict__ in, unsigned short* __restrict__ out, int n8)
{
    for (int i = blockIdx.x * blockDim.x + threadIdx.x; i < n8;
         i += gridDim.x * blockDim.x) {
        const float4 a = ((const float4*)in)[2 * i];
        const float4 b = ((const float4*)in)[2 * i + 1];
        u16x8 o;
        o[0] = f2bf(a.x); o[1] = f2bf(a.y); o[2] = f2bf(a.z); o[3] = f2bf(a.w);
        o[4] = f2bf(b.x); o[5] = f2bf(b.y); o[6] = f2bf(b.z); o[7] = f2bf(b.w);
        ((u16x8*)out)[i] = o;
    }
}

// out[cols][rows] (bf16) = transpose(in[rows][cols] f32)
__global__ __launch_bounds__(256) void tconv_f32_bf16(
    const float* __restrict__ in, unsigned short* __restrict__ out,
    int rows, int cols)
{
    __shared__ float t[32][33];
    const int c0 = blockIdx.x * 32, r0 = blockIdx.y * 32;
    const int tx = threadIdx.x & 31, ty = threadIdx.x >> 5;
#pragma unroll
    for (int i = 0; i < 4; i++)
        t[ty + 8 * i][tx] = in[(long long)(r0 + ty + 8 * i) * cols + c0 + tx];
    __syncthreads();
#pragma unroll
    for (int i = 0; i < 4; i++)
        out[(long long)(c0 + ty + 8 * i) * rows + r0 + tx] = f2bf(t[tx][ty + 8 * i]);
}

// bf16 transpose, batched via grid.z
__global__ __launch_bounds__(256) void t_bf16(
    const unsigned short* __restrict__ in, unsigned short* __restrict__ out,
    int rows, int cols, long long sIz, long long sOz)
{
    __shared__ unsigned short t[32][33];
    in  += blockIdx.z * sIz;
    out += blockIdx.z * sOz;
    const int c0 = blockIdx.x * 32, r0 = blockIdx.y * 32;
    const int tx = threadIdx.x & 31, ty = threadIdx.x >> 5;
#pragma unroll
    for (int i = 0; i < 4; i++)
        t[ty + 8 * i][tx] = in[(long long)(r0 + ty + 8 * i) * cols + c0 + tx];
    __syncthreads();
#pragma unroll
    for (int i = 0; i < 4; i++)
        out[(long long)(c0 + ty + 8 * i) * rows + r0 + tx] = t[tx][ty + 8 * i];
}

// in-place row softmax over S_=2048 bf16 logits; one block (256 thr) per row
__global__ __launch_bounds__(256) void softmax_rows(unsigned short* __restrict__ sc)
{
    const long long row = blockIdx.x;
    unsigned short* p = sc + row * S_;
    const int tid = threadIdx.x, w = tid >> 6, l = tid & 63;

    u16x8 v = *reinterpret_cast<const u16x8*>(&p[tid * 8]);
    float f[8];
#pragma unroll
    for (int i = 0; i < 8; i++) f[i] = bf2f(v[i]);

    float m = f[0];
#pragma unroll
    for (int i = 1; i < 8; i++) m = fmaxf(m, f[i]);
    for (int o = 32; o; o >>= 1) m = fmaxf(m, __shfl_xor(m, o));
    __shared__ float red[8];
    if (l == 0) red[w] = m;
    __syncthreads();
    m = fmaxf(fmaxf(red[0], red[1]), fmaxf(red[2], red[3]));

    float s = 0.f;
#pragma unroll
    for (int i = 0; i < 8; i++) { f[i] = __expf(f[i] - m); s += f[i]; }
    for (int o = 32; o; o >>= 1) s += __shfl_xor(s, o);
    if (l == 0) red[4 + w] = s;
    __syncthreads();
    s = red[4] + red[5] + red[6] + red[7];

    const float inv = 1.0f / s;
    u16x8 o8;
#pragma unroll
    for (int i = 0; i < 8; i++) o8[i] = f2bf(f[i] * inv);
    *reinterpret_cast<u16x8*>(&p[tid * 8]) = o8;
}

extern "C" void kernel_launch(void* const* d_in, const int* in_sizes, int n_in,
                              void* d_out, int out_size, void* d_ws, size_t ws_size,
                              hipStream_t stream)
{
    (void)in_sizes; (void)n_in; (void)out_size; (void)ws_size;
    const float* x  = (const float*)d_in[0];
    const float* W1 = (const float*)d_in[1];
    const float* b1 = (const float*)d_in[2];
    const float* W2 = (const float*)d_in[3];
    const float* b2 = (const float*)d_in[4];
    float* out = (float*)d_out;

    char* ws = (char*)d_ws;
    size_t off = 0;
    auto alloc = [&](size_t bytes) {
        void* p = ws + off;
        off += (bytes + 255) & ~(size_t)255;
        return p;
    };
    unsigned short* xbf = (unsigned short*)alloc((size_t)BS_ * D_ * 2);
    unsigned short* w1t = (unsigned short*)alloc((size_t)N3H * D_ * 2);
    unsigned short* w2t = (unsigned short*)alloc((size_t)H_ * H_ * 2);
    unsigned short* q   = (unsigned short*)alloc((size_t)BS_ * H_ * 2);
    unsigned short* k   = (unsigned short*)alloc((size_t)BS_ * H_ * 2);
    unsigned short* v   = (unsigned short*)alloc((size_t)BS_ * H_ * 2);
    unsigned short* vt  = (unsigned short*)alloc((size_t)BS_ * H_ * 2);
    unsigned short* sc  = (unsigned short*)alloc((size_t)B_ * S_ * S_ * 2);
    unsigned short* ctx = v;  // alias: v is dead after transpose, before PV writes

    const float scale = 0.022097086912079608f;  // (2*D)^-0.5 = 1/sqrt(2048)

    conv_f32_bf16<<<dim3(2048), dim3(256), 0, stream>>>(x, xbf, BS_ * D_ / 8);
    tconv_f32_bf16<<<dim3(N3H / 32, D_ / 32), dim3(256), 0, stream>>>(W1, w1t, D_, N3H);
    tconv_f32_bf16<<<dim3(H_ / 32, H_ / 32), dim3(256), 0, stream>>>(W2, w2t, H_, H_);

    // QKV: [8192,3072] = xbf @ w1t^T, split into q/k/v, +b1
    gemm256<0><<<dim3(N3H / 256, BS_ / 256, 1), dim3(512), 0, stream>>>(
        xbf, w1t, BS_, N3H, D_, 0LL, 0LL, 0LL, q, k, v, b1, 1.0f);

    // vt[b][h][s] = v[b][s][h]
    t_bf16<<<dim3(H_ / 32, S_ / 32, B_), dim3(256), 0, stream>>>(
        v, vt, S_, H_, (long long)S_ * H_, (long long)S_ * H_);

    // scores[b] = (q[b] @ k[b]^T) * scale   [2048,2048] bf16
    gemm256<1><<<dim3(S_ / 256, S_ / 256, B_), dim3(512), 0, stream>>>(
        q, k, S_, S_, H_, (long long)S_ * H_, (long long)S_ * H_, (long long)S_ * S_,
        sc, nullptr, nullptr, nullptr, scale);

    softmax_rows<<<dim3(BS_), dim3(256), 0, stream>>>(sc);

    // ctx[b] = P[b] @ vt[b]^T   [2048,1024] bf16
    gemm256<1><<<dim3(H_ / 256, S_ / 256, B_), dim3(512), 0, stream>>>(
        sc, vt, S_, H_, S_, (long long)S_ * S_, (long long)H_ * S_, (long long)S_ * H_,
        ctx, nullptr, nullptr, nullptr, 1.0f);

    // out = ctx @ w2t^T + b2   [8192,1024] f32
    gemm256<3><<<dim3(H_ / 256, BS_ / 256, 1), dim3(512), 0, stream>>>(
        ctx, w2t, BS_, H_, H_, 0LL, 0LL, 0LL, out, nullptr, nullptr, b2, 1.0f);
}

// Round 3
// 213.683 us; speedup vs baseline: 1.2751x; 1.1233x over previous
//
#include <hip/hip_runtime.h>
#include <hip/hip_bf16.h>
#include <stdint.h>

#define B_  4
#define S_  2048
#define D_  1024
#define H_  1024
#define BS_ (B_*S_)    // 8192
#define N3H (3*H_)     // 3072

typedef __bf16 bf16x8 __attribute__((ext_vector_type(8)));
typedef float  f32x4  __attribute__((ext_vector_type(4)));
typedef unsigned short u16x8 __attribute__((ext_vector_type(8)));

__device__ __forceinline__ unsigned short f2bf(float x) {
    unsigned u = __float_as_uint(x);
    return (unsigned short)((u + 0x7FFFu + ((u >> 16) & 1u)) >> 16);  // RNE
}
__device__ __forceinline__ float bf2f(unsigned short h) {
    return __uint_as_float(((unsigned)h) << 16);
}

__device__ __forceinline__ void gload_lds16(const void* g, void* l) {
    __builtin_amdgcn_global_load_lds(
        (const __attribute__((address_space(1))) void*)g,
        (__attribute__((address_space(3))) void*)l, 16, 0, 0);
}

#define BAR __builtin_amdgcn_s_barrier()
#define DS_FENCE do { asm volatile("s_waitcnt lgkmcnt(0)" ::: "memory"); \
                      __builtin_amdgcn_sched_barrier(0); } while (0)

// ---------------------------------------------------------------------------
// gemm128: 256x128-tile bt-GEMM, triple-buffered, 2 phases per K-tile.
// C[M,N] = A[M,K] @ B[N,K]^T, bf16 in, f32 accum. BK=64, 8 waves (2Mx4N),
// wave-tile 128x32 (acc 8x2), 512 threads, 144 KiB LDS (3 bufs x 48 KiB:
// A0 16K | A1 16K | B0 8K | B1 8K). st_16x32 swizzle (same as gemm256).
// Schedule per K-tile t (buf b=t%3, stage buf s=(t+2)%3, distinct from b,b+1):
//  ph1: ds_read A-lo(8)+B(4); STAGE s.A0(2)+s.B0(1); BAR; lgkm; 16 MFMA; BAR
//  ph2: ds_read A-hi(8);      STAGE s.A1(2)+s.B1(1); BAR; lgkm; 16 MFMA;
//       vmcnt(6) [drains tile t+1's 6 loads, leaves t+2's 6 in flight]; BAR
// Tile-id 1D grid, XCD-swizzled (ntiles % 8 == 0 for every launch here).
// ---------------------------------------------------------------------------
template<int EPI>
__global__ __launch_bounds__(512, 2) void gemm128(
    const unsigned short* __restrict__ A,
    const unsigned short* __restrict__ Bm,
    int NXt, int NYt, int N, int K,
    long long sAz, long long sBz, long long sOz,
    void* __restrict__ out0, void* __restrict__ out1, void* __restrict__ out2,
    const float* __restrict__ bias, float scale)
{
    __shared__ __align__(16) char lds[3 * 49152];

    // XCD swizzle: consecutive hardware blocks round-robin XCDs; remap so each
    // XCD gets a contiguous tile chunk (ty-major => A-panel reuse per XCD)
    const int nt_g = (int)gridDim.x;
    const int bid = (int)blockIdx.x;
    const int tile = (bid & 7) * (nt_g >> 3) + (bid >> 3);
    const int tx = tile % NXt;
    const int rest = tile / NXt;
    const int ty = rest % NYt;
    const int tz = rest / NYt;

    const unsigned short* Ab = A  + (long long)tz * sAz;
    const unsigned short* Bb = Bm + (long long)tz * sBz;
    const int rowBase = ty * 256;
    const int colBase = tx * 128;
    const int tid = threadIdx.x;
    const int w = tid >> 6, l = tid & 63;
    const int wr = w >> 2, wc = w & 3;          // 2M x 4N waves
    const int fr = l & 15, fq = l >> 4;

    // staging source decode (inverse st_16x32 swizzle), same as gemm256
    int sr[2], scl[2];
#pragma unroll
    for (int j = 0; j < 2; j++) {
        int o  = j * 8192 + tid * 16;
        int st = o >> 10;
        int wi = o & 1023;
        wi ^= ((wi >> 9) & 1) << 5;
        sr[j]  = (st >> 1) * 16 + (wi >> 6);
        scl[j] = (st & 1) * 32 + ((wi & 63) >> 1);
    }

    auto STAGE_A = [&](char* buf, int half, int t) {
        char* dst = buf + half * 16384 + w * 1024;
        const unsigned short* base =
            Ab + (long long)(rowBase + half * 128) * K + t * 64;
#pragma unroll
        for (int j = 0; j < 2; j++)
            gload_lds16(base + (long long)sr[j] * K + scl[j], dst + j * 8192);
    };
    auto STAGE_B = [&](char* buf, int half, int t) {
        char* dst = buf + 32768 + half * 8192 + w * 1024;
        const unsigned short* base =
            Bb + (long long)(colBase + half * 64) * K + t * 64;
        gload_lds16(base + (long long)sr[0] * K + scl[0], dst);
    };

    const int abase = (fr * 64 + fq * 16) ^ ((fr & 8) << 2);

#define MFMA82(AF, BF, MOFF) do { \
    __builtin_amdgcn_s_setprio(1); \
    _Pragma("unroll") for (int m_ = 0; m_ < 4; m_++) \
    _Pragma("unroll") for (int n_ = 0; n_ < 2; n_++) \
    _Pragma("unroll") for (int k_ = 0; k_ < 2; k_++) \
        acc[(MOFF)+m_][n_] = __builtin_amdgcn_mfma_f32_16x16x32_bf16( \
            AF[m_][k_], BF[n_][k_], acc[(MOFF)+m_][n_], 0, 0, 0); \
    __builtin_amdgcn_s_setprio(0); } while (0)

    f32x4 acc[8][2];
#pragma unroll
    for (int m = 0; m < 8; m++)
#pragma unroll
        for (int n = 0; n < 2; n++) acc[m][n] = (f32x4){0.f, 0.f, 0.f, 0.f};

    const int NT = K >> 6;

    // prologue: tiles 0 (buf0) and 1 (buf1) fully; drain tile0's 6 loads
    STAGE_A(lds, 0, 0); STAGE_B(lds, 0, 0); STAGE_A(lds, 1, 0); STAGE_B(lds, 1, 0);
    STAGE_A(lds + 49152, 0, 1); STAGE_B(lds + 49152, 0, 1);
    STAGE_A(lds + 49152, 1, 1); STAGE_B(lds + 49152, 1, 1);
    asm volatile("s_waitcnt vmcnt(6)" ::: "memory");
    BAR;
    __builtin_amdgcn_sched_barrier(0);

    bf16x8 afA[4][2], afB[4][2], bf[2][2];

    for (int t = 0; t < NT; ++t) {
        const char* bc = lds + (t % 3) * 49152;
        char* bs = lds + ((t + 2) % 3) * 49152;
        int ts = t + 2; if (ts >= NT) ts -= NT;
        const char* Abw = bc + wr * 16384;
        const char* Bbw = bc + 32768 + (wc >> 1) * 8192 + (wc & 1) * 4096;

        // ph1: A-lo + B
#pragma unroll
        for (int m = 0; m < 4; m++)
#pragma unroll
            for (int kk = 0; kk < 2; kk++)
                afA[m][kk] = *(const bf16x8*)(Abw + m * 2048 + kk * 1024 + abase);
#pragma unroll
        for (int n = 0; n < 2; n++)
#pragma unroll
            for (int kk = 0; kk < 2; kk++)
                bf[n][kk] = *(const bf16x8*)(Bbw + n * 2048 + kk * 1024 + abase);
        STAGE_A(bs, 0, ts); STAGE_B(bs, 0, ts);
        BAR; DS_FENCE;
        MFMA82(afA, bf, 0);
        BAR;

        // ph2: A-hi
#pragma unroll
        for (int m = 0; m < 4; m++)
#pragma unroll
            for (int kk = 0; kk < 2; kk++)
                afB[m][kk] = *(const bf16x8*)(Abw + (m + 4) * 2048 + kk * 1024 + abase);
        STAGE_A(bs, 1, ts); STAGE_B(bs, 1, ts);
        BAR; DS_FENCE;
        MFMA82(afB, bf, 4);
        asm volatile("s_waitcnt vmcnt(6)" ::: "memory");
        BAR;
        __builtin_amdgcn_sched_barrier(0);
    }

    asm volatile("s_waitcnt vmcnt(0) lgkmcnt(0)" ::: "memory");

    // epilogue: row = rowBase + wr*128 + m*16 + fq*4 + j; col = colBase + wc*32 + n*16 + fr
    const int crow0 = rowBase + wr * 128 + fq * 4;
    const int ccol0 = colBase + wc * 32 + fr;

#pragma unroll
    for (int n = 0; n < 2; n++) {
        const int col = ccol0 + n * 16;
        if constexpr (EPI == 0) {
            const float bv = bias[col];
            const int seg = col >> 10, scn = col & 1023;
            unsigned short* dst =
                (unsigned short*)(seg == 0 ? out0 : (seg == 1 ? out1 : out2));
#pragma unroll
            for (int m = 0; m < 8; m++) {
                const int r0 = crow0 + m * 16;
#pragma unroll
                for (int j = 0; j < 4; j++)
                    dst[(long long)(r0 + j) * 1024 + scn] = f2bf(acc[m][n][j] + bv);
            }
        } else if constexpr (EPI == 1) {
            unsigned short* dst = (unsigned short*)out0 + (long long)tz * sOz;
#pragma unroll
            for (int m = 0; m < 8; m++) {
                const int r0 = crow0 + m * 16;
#pragma unroll
                for (int j = 0; j < 4; j++)
                    dst[(long long)(r0 + j) * N + col] = f2bf(acc[m][n][j] * scale);
            }
        } else {
            float* dst = (float*)out0;
            const float bv = bias[col];
#pragma unroll
            for (int m = 0; m < 8; m++) {
                const int r0 = crow0 + m * 16;
#pragma unroll
                for (int j = 0; j < 4; j++)
                    dst[(long long)(r0 + j) * N + col] = acc[m][n][j] + bv;
            }
        }
    }
#undef MFMA82
}

// ---------------------------------------------------------------------------
// gemm256: verified 256x256 8-phase kernel (round 2) — kept for scores
// ---------------------------------------------------------------------------
template<int EPI>
__global__ __launch_bounds__(512, 2) void gemm256(
    const unsigned short* __restrict__ A,
    const unsigned short* __restrict__ Bm,
    int M, int N, int K,
    long long sAz, long long sBz, long long sOz,
    void* __restrict__ out0, void* __restrict__ out1, void* __restrict__ out2,
    const float* __restrict__ bias, float scale)
{
    __shared__ __align__(16) char lds[131072];
    (void)M;

    const unsigned short* Ab = A  + blockIdx.z * sAz;
    const unsigned short* Bb = Bm + blockIdx.z * sBz;
    const int rowBase = blockIdx.y * 256;
    const int colBase = blockIdx.x * 256;
    const int tid = threadIdx.x;
    const int w = tid >> 6, l = tid & 63;
    const int wr = w >> 2, wc = w & 3;
    const int fr = l & 15, fq = l >> 4;

    int sr[2], scl[2];
#pragma unroll
    for (int j = 0; j < 2; j++) {
        int o  = j * 8192 + tid * 16;
        int st = o >> 10;
        int wi = o & 1023;
        wi ^= ((wi >> 9) & 1) << 5;
        sr[j]  = (st >> 1) * 16 + (wi >> 6);
        scl[j] = (st & 1) * 32 + ((wi & 63) >> 1);
    }

    auto STAGE = [&](int buf, int which, int tile) {
        const unsigned short* mat = (which < 2) ? Ab : Bb;
        const int rt0 = ((which < 2) ? rowBase : colBase) + (which & 1) * 128;
        char* dst = lds + buf * 65536 + (which >> 1) * 32768
                        + (which & 1) * 16384 + w * 1024;
        const int k0 = tile * 64;
#pragma unroll
        for (int j = 0; j < 2; j++) {
            const unsigned short* src =
                mat + (long long)(rt0 + sr[j]) * K + k0 + scl[j];
            gload_lds16(src, dst + j * 8192);
        }
    };

    const int abase = (fr * 64 + fq * 16) ^ ((fr & 8) << 2);
    const char* Ah[2] = { lds + wr * 16384, lds + 65536 + wr * 16384 };
    const char* Bh[2] = { lds + 32768 + (wc >> 1) * 16384,
                          lds + 98304 + (wc >> 1) * 16384 };
    const int bn0 = (wc & 1) * 8192;

#define LA(b, m, kk) (*(const bf16x8*)(Ah[b] + (m)*2048 + (kk)*1024 + abase))
#define LB(b, n, kk) (*(const bf16x8*)(Bh[b] + bn0 + (n)*2048 + (kk)*1024 + abase))
#define MFMA16(AF, BF, MOFF, NOFF) do { \
    __builtin_amdgcn_s_setprio(1); \
    _Pragma("unroll") for (int m_ = 0; m_ < 4; m_++) \
    _Pragma("unroll") for (int n_ = 0; n_ < 2; n_++) \
    _Pragma("unroll") for (int k_ = 0; k_ < 2; k_++) \
        acc[(MOFF)+m_][(NOFF)+n_] = __builtin_amdgcn_mfma_f32_16x16x32_bf16( \
            AF[m_][k_], BF[n_][k_], acc[(MOFF)+m_][(NOFF)+n_], 0, 0, 0); \
    __builtin_amdgcn_s_setprio(0); } while (0)

    f32x4 acc[8][4];
#pragma unroll
    for (int m = 0; m < 8; m++)
#pragma unroll
        for (int n = 0; n < 4; n++) acc[m][n] = (f32x4){0.f, 0.f, 0.f, 0.f};

    const int NT = K >> 6;

    STAGE(0, 0, 0); STAGE(0, 1, 0); STAGE(0, 2, 0); STAGE(0, 3, 0);
    STAGE(1, 0, 1); STAGE(1, 1, 1);
    asm volatile("s_waitcnt vmcnt(4)" ::: "memory");
    BAR;
    __builtin_amdgcn_sched_barrier(0);

    bf16x8 afA[4][2], afB[4][2], bfA[2][2], bfB[2][2];

    for (int i = 0; i < NT / 2; i++) {
        const int t1 = 2 * i + 1;
        int t2 = 2 * i + 2; if (t2 >= NT) t2 -= NT;
        int t3 = 2 * i + 3; if (t3 >= NT) t3 -= NT;

#pragma unroll
        for (int m = 0; m < 4; m++) { afA[m][0] = LA(0, m, 0); afA[m][1] = LA(0, m, 1); }
#pragma unroll
        for (int n = 0; n < 2; n++) { bfA[n][0] = LB(0, n, 0); bfA[n][1] = LB(0, n, 1); }
        STAGE(1, 2, t1);
        BAR; DS_FENCE;
        MFMA16(afA, bfA, 0, 0);
        BAR;
#pragma unroll
        for (int m = 0; m < 4; m++) { afB[m][0] = LA(0, 4 + m, 0); afB[m][1] = LA(0, 4 + m, 1); }
        STAGE(1, 3, t1);
        BAR; DS_FENCE;
        MFMA16(afB, bfA, 4, 0);
        BAR;
#pragma unroll
        for (int n = 0; n < 2; n++) { bfB[n][0] = LB(0, 2 + n, 0); bfB[n][1] = LB(0, 2 + n, 1); }
        STAGE(0, 0, t2);
        BAR; DS_FENCE;
        MFMA16(afA, bfB, 0, 2);
        BAR;
        STAGE(0, 1, t2);
        BAR;
        MFMA16(afB, bfB, 4, 2);
        asm volatile("s_waitcnt vmcnt(4)" ::: "memory");
        BAR;
        __builtin_amdgcn_sched_barrier(0);

#pragma unroll
        for (int m = 0; m < 4; m++) { afA[m][0] = LA(1, m, 0); afA[m][1] = LA(1, m, 1); }
#pragma unroll
        for (int n = 0; n < 2; n++) { bfA[n][0] = LB(1, n, 0); bfA[n][1] = LB(1, n, 1); }
        STAGE(0, 2, t2);
        BAR; DS_FENCE;
        MFMA16(afA, bfA, 0, 0);
        BAR;
#pragma unroll
        for (int m = 0; m < 4; m++) { afB[m][0] = LA(1, 4 + m, 0); afB[m][1] = LA(1, 4 + m, 1); }
        STAGE(0, 3, t2);
        BAR; DS_FENCE;
        MFMA16(afB, bfA, 4, 0);
        BAR;
#pragma unroll
        for (int n = 0; n < 2; n++) { bfB[n][0] = LB(1, 2 + n, 0); bfB[n][1] = LB(1, 2 + n, 1); }
        STAGE(1, 0, t3);
        BAR; DS_FENCE;
        MFMA16(afA, bfB, 0, 2);
        BAR;
        STAGE(1, 1, t3);
        BAR;
        MFMA16(afB, bfB, 4, 2);
        asm volatile("s_waitcnt vmcnt(4)" ::: "memory");
        BAR;
        __builtin_amdgcn_sched_barrier(0);
    }

    asm volatile("s_waitcnt vmcnt(0) lgkmcnt(0)" ::: "memory");

    const int crow0 = rowBase + wr * 128 + fq * 4;
    const int ccol0 = colBase + wc * 64 + fr;

#pragma unroll
    for (int n = 0; n < 4; n++) {
        const int col = ccol0 + n * 16;
        if constexpr (EPI == 1) {
            unsigned short* dst = (unsigned short*)out0 + blockIdx.z * sOz;
#pragma unroll
            for (int m = 0; m < 8; m++) {
                const int r0 = crow0 + m * 16;
#pragma unroll
                for (int j = 0; j < 4; j++)
                    dst[(long long)(r0 + j) * N + col] = f2bf(acc[m][n][j] * scale);
            }
        }
    }
    (void)out1; (void)out2; (void)bias;
#undef LA
#undef LB
#undef MFMA16
}

// f32 -> bf16 elementwise (8/thread, vectorized)
__global__ __launch_bounds__(256) void conv_f32_bf16(
    const float* __restrict__ in, unsigned short* __restrict__ out, int n8)
{
    for (int i = blockIdx.x * blockDim.x + threadIdx.x; i < n8;
         i += gridDim.x * blockDim.x) {
        const float4 a = ((const float4*)in)[2 * i];
        const float4 b = ((const float4*)in)[2 * i + 1];
        u16x8 o;
        o[0] = f2bf(a.x); o[1] = f2bf(a.y); o[2] = f2bf(a.z); o[3] = f2bf(a.w);
        o[4] = f2bf(b.x); o[5] = f2bf(b.y); o[6] = f2bf(b.z); o[7] = f2bf(b.w);
        ((u16x8*)out)[i] = o;
    }
}

// out[cols][rows] (bf16) = transpose(in[rows][cols] f32)
__global__ __launch_bounds__(256) void tconv_f32_bf16(
    const float* __restrict__ in, unsigned short* __restrict__ out,
    int rows, int cols)
{
    __shared__ float t[32][33];
    const int c0 = blockIdx.x * 32, r0 = blockIdx.y * 32;
    const int tx = threadIdx.x & 31, ty = threadIdx.x >> 5;
#pragma unroll
    for (int i = 0; i < 4; i++)
        t[ty + 8 * i][tx] = in[(long long)(r0 + ty + 8 * i) * cols + c0 + tx];
    __syncthreads();
#pragma unroll
    for (int i = 0; i < 4; i++)
        out[(long long)(c0 + ty + 8 * i) * rows + r0 + tx] = f2bf(t[tx][ty + 8 * i]);
}

// bf16 transpose, batched via grid.z
__global__ __launch_bounds__(256) void t_bf16(
    const unsigned short* __restrict__ in, unsigned short* __restrict__ out,
    int rows, int cols, long long sIz, long long sOz)
{
    __shared__ unsigned short t[32][33];
    in  += blockIdx.z * sIz;
    out += blockIdx.z * sOz;
    const int c0 = blockIdx.x * 32, r0 = blockIdx.y * 32;
    const int tx = threadIdx.x & 31, ty = threadIdx.x >> 5;
#pragma unroll
    for (int i = 0; i < 4; i++)
        t[ty + 8 * i][tx] = in[(long long)(r0 + ty + 8 * i) * cols + c0 + tx];
    __syncthreads();
#pragma unroll
    for (int i = 0; i < 4; i++)
        out[(long long)(c0 + ty + 8 * i) * rows + r0 + tx] = t[tx][ty + 8 * i];
}

// in-place row softmax over S_=2048 bf16 logits; one block (256 thr) per row
__global__ __launch_bounds__(256) void softmax_rows(unsigned short* __restrict__ sc)
{
    const long long row = blockIdx.x;
    unsigned short* p = sc + row * S_;
    const int tid = threadIdx.x, w = tid >> 6, l = tid & 63;

    u16x8 v = *reinterpret_cast<const u16x8*>(&p[tid * 8]);
    float f[8];
#pragma unroll
    for (int i = 0; i < 8; i++) f[i] = bf2f(v[i]);

    float m = f[0];
#pragma unroll
    for (int i = 1; i < 8; i++) m = fmaxf(m, f[i]);
    for (int o = 32; o; o >>= 1) m = fmaxf(m, __shfl_xor(m, o));
    __shared__ float red[8];
    if (l == 0) red[w] = m;
    __syncthreads();
    m = fmaxf(fmaxf(red[0], red[1]), fmaxf(red[2], red[3]));

    float s = 0.f;
#pragma unroll
    for (int i = 0; i < 8; i++) { f[i] = __expf(f[i] - m); s += f[i]; }
    for (int o = 32; o; o >>= 1) s += __shfl_xor(s, o);
    if (l == 0) red[4 + w] = s;
    __syncthreads();
    s = red[4] + red[5] + red[6] + red[7];

    const float inv = 1.0f / s;
    u16x8 o8;
#pragma unroll
    for (int i = 0; i < 8; i++) o8[i] = f2bf(f[i] * inv);
    *reinterpret_cast<u16x8*>(&p[tid * 8]) = o8;
}

extern "C" void kernel_launch(void* const* d_in, const int* in_sizes, int n_in,
                              void* d_out, int out_size, void* d_ws, size_t ws_size,
                              hipStream_t stream)
{
    (void)in_sizes; (void)n_in; (void)out_size; (void)ws_size;
    const float* x  = (const float*)d_in[0];
    const float* W1 = (const float*)d_in[1];
    const float* b1 = (const float*)d_in[2];
    const float* W2 = (const float*)d_in[3];
    const float* b2 = (const float*)d_in[4];
    float* out = (float*)d_out;

    char* ws = (char*)d_ws;
    size_t off = 0;
    auto alloc = [&](size_t bytes) {
        void* p = ws + off;
        off += (bytes + 255) & ~(size_t)255;
        return p;
    };
    unsigned short* xbf = (unsigned short*)alloc((size_t)BS_ * D_ * 2);
    unsigned short* w1t = (unsigned short*)alloc((size_t)N3H * D_ * 2);
    unsigned short* w2t = (unsigned short*)alloc((size_t)H_ * H_ * 2);
    unsigned short* q   = (unsigned short*)alloc((size_t)BS_ * H_ * 2);
    unsigned short* k   = (unsigned short*)alloc((size_t)BS_ * H_ * 2);
    unsigned short* v   = (unsigned short*)alloc((size_t)BS_ * H_ * 2);
    unsigned short* vt  = (unsigned short*)alloc((size_t)BS_ * H_ * 2);
    unsigned short* sc  = (unsigned short*)alloc((size_t)B_ * S_ * S_ * 2);
    unsigned short* ctx = v;  // alias: v is dead after transpose, before PV writes

    const float scale = 0.022097086912079608f;  // (2*D)^-0.5 = 1/sqrt(2048)

    conv_f32_bf16<<<dim3(2048), dim3(256), 0, stream>>>(x, xbf, BS_ * D_ / 8);
    tconv_f32_bf16<<<dim3(N3H / 32, D_ / 32), dim3(256), 0, stream>>>(W1, w1t, D_, N3H);
    tconv_f32_bf16<<<dim3(H_ / 32, H_ / 32), dim3(256), 0, stream>>>(W2, w2t, H_, H_);

    // QKV: [8192,3072] = xbf @ w1t^T, split q/k/v, +b1.  24x32 = 768 tiles = 3.0/CU
    gemm128<0><<<dim3(768), dim3(512), 0, stream>>>(
        xbf, w1t, 24, 32, N3H, D_, 0LL, 0LL, 0LL, q, k, v, b1, 1.0f);

    // vt[b][h][s] = v[b][s][h]
    t_bf16<<<dim3(H_ / 32, S_ / 32, B_), dim3(256), 0, stream>>>(
        v, vt, S_, H_, (long long)S_ * H_, (long long)S_ * H_);

    // scores[b] = (q[b] @ k[b]^T) * scale  [2048,2048] bf16 — 256 blocks = 1.0/CU
    gemm256<1><<<dim3(S_ / 256, S_ / 256, B_), dim3(512), 0, stream>>>(
        q, k, S_, S_, H_, (long long)S_ * H_, (long long)S_ * H_, (long long)S_ * S_,
        sc, nullptr, nullptr, nullptr, scale);

    softmax_rows<<<dim3(BS_), dim3(256), 0, stream>>>(sc);

    // ctx[b] = P[b] @ vt[b]^T  [2048,1024] bf16.  8x8x4 = 256 tiles = 1.0/CU
    gemm128<1><<<dim3(256), dim3(512), 0, stream>>>(
        sc, vt, 8, 8, H_, S_, (long long)S_ * S_, (long long)H_ * S_,
        (long long)S_ * H_, ctx, nullptr, nullptr, nullptr, 1.0f);

    // out = ctx @ w2t^T + b2  [8192,1024] f32.  8x32 = 256 tiles = 1.0/CU
    gemm128<3><<<dim3(256), dim3(512), 0, stream>>>(
        ctx, w2t, 8, 32, H_, H_, 0LL, 0LL, 0LL, out, nullptr, nullptr, b2, 1.0f);
}

// Round 4
// 206.406 us; speedup vs baseline: 1.3200x; 1.0353x over previous
//
#include <hip/hip_runtime.h>
#include <hip/hip_bf16.h>
#include <stdint.h>

#define B_  4
#define S_  2048
#define D_  1024
#define H_  1024
#define BS_ (B_*S_)    // 8192
#define N3H (3*H_)     // 3072

typedef __bf16 bf16x8 __attribute__((ext_vector_type(8)));
typedef float  f32x4  __attribute__((ext_vector_type(4)));
typedef unsigned short u16x8 __attribute__((ext_vector_type(8)));

__device__ __forceinline__ unsigned short f2bf(float x) {
    unsigned u = __float_as_uint(x);
    return (unsigned short)((u + 0x7FFFu + ((u >> 16) & 1u)) >> 16);  // RNE
}
__device__ __forceinline__ float bf2f(unsigned short h) {
    return __uint_as_float(((unsigned)h) << 16);
}

__device__ __forceinline__ void gload_lds16(const void* g, void* l) {
    __builtin_amdgcn_global_load_lds(
        (const __attribute__((address_space(1))) void*)g,
        (__attribute__((address_space(3))) void*)l, 16, 0, 0);
}

#define BAR __builtin_amdgcn_s_barrier()
#define DS_FENCE do { asm volatile("s_waitcnt lgkmcnt(0)" ::: "memory"); \
                      __builtin_amdgcn_sched_barrier(0); } while (0)

// ---------------------------------------------------------------------------
// gemm128: 256x128-tile bt-GEMM, triple-buffered, 2 phases per K-tile.
// C[M,N] = A[M,K] @ B[N,K]^T, bf16 in, f32 accum. BK=64, 8 waves as 4Mx2N
// (wave-tile 64x64, acc 4x4) -> 16 ds_read_b128 per 32 MFMA per K-tile
// (ratio 0.5 vs round-3's 0.625 -- LDS-read pipe was the binding constraint).
// 512 threads, 144 KiB LDS (3 bufs x 48 KiB: A0 16K | A1 16K | B0 8K | B1 8K),
// st_16x32 swizzle. Schedule per K-tile t (read buf t%3, stage buf (t+2)%3):
//  ph1: ds_read A all (8) + B n0-1 (4); STAGE A0+B0; BAR; lgkm; 16 MFMA; BAR
//  ph2: ds_read B n2-3 (4);             STAGE A1+B1; BAR; lgkm; 16 MFMA;
//       vmcnt(6) [drains tile t+1's 6 loads, leaves t+2's 6 in flight]; BAR
// Grid: 1D, XCD-chunked (bid&7 -> XCD), 2D sub-chunk order within each chunk
// (4 row-groups x cols, column-grouped) for <=4MB concurrent L2 footprint.
// Requires gridDim.x % 8 == 0 and (gridDim.x/8) % (4*NXt) == 0.
// ---------------------------------------------------------------------------
template<int EPI>
__global__ __launch_bounds__(512, 2) void gemm128(
    const unsigned short* __restrict__ A,
    const unsigned short* __restrict__ Bm,
    int NXt, int NYt, int N, int K,
    long long sAz, long long sBz, long long sOz,
    void* __restrict__ out0, void* __restrict__ out1, void* __restrict__ out2,
    const float* __restrict__ bias, float scale)
{
    __shared__ __align__(16) char lds[3 * 49152];

    // XCD chunking + within-chunk 2D sub-order
    const int nt_g = (int)gridDim.x;
    const int bid = (int)blockIdx.x;
    const int C = nt_g >> 3;
    const int c = bid >> 3;
    const int xcd = bid & 7;
    const int qq = c >> 2;
    const int txl = qq % NXt;
    const int rest = (c & 3) + 4 * (qq / NXt);
    const int tile = xcd * C + rest * NXt + txl;
    const int tx = tile % NXt;
    const int rest2 = tile / NXt;
    const int ty = rest2 % NYt;
    const int tz = rest2 / NYt;

    const unsigned short* Ab = A  + (long long)tz * sAz;
    const unsigned short* Bb = Bm + (long long)tz * sBz;
    const int rowBase = ty * 256;
    const int colBase = tx * 128;
    const int tid = threadIdx.x;
    const int w = tid >> 6, l = tid & 63;
    const int wr = w >> 1, wc = w & 1;          // 4M x 2N waves
    const int fr = l & 15, fq = l >> 4;

    // staging source decode (inverse st_16x32 swizzle)
    int sr[2], scl[2];
#pragma unroll
    for (int j = 0; j < 2; j++) {
        int o  = j * 8192 + tid * 16;
        int st = o >> 10;
        int wi = o & 1023;
        wi ^= ((wi >> 9) & 1) << 5;
        sr[j]  = (st >> 1) * 16 + (wi >> 6);
        scl[j] = (st & 1) * 32 + ((wi & 63) >> 1);
    }

    auto STAGE_A = [&](char* buf, int half, int t) {
        char* dst = buf + half * 16384 + w * 1024;
        const unsigned short* base =
            Ab + (long long)(rowBase + half * 128) * K + t * 64;
#pragma unroll
        for (int j = 0; j < 2; j++)
            gload_lds16(base + (long long)sr[j] * K + scl[j], dst + j * 8192);
    };
    auto STAGE_B = [&](char* buf, int half, int t) {
        char* dst = buf + 32768 + half * 8192 + w * 1024;
        const unsigned short* base =
            Bb + (long long)(colBase + half * 64) * K + t * 64;
        gload_lds16(base + (long long)sr[0] * K + scl[0], dst);
    };

    const int abase = (fr * 64 + fq * 16) ^ ((fr & 8) << 2);

#define MFMA44(AF, BF, NOFF) do { \
    __builtin_amdgcn_s_setprio(1); \
    _Pragma("unroll") for (int m_ = 0; m_ < 4; m_++) \
    _Pragma("unroll") for (int n_ = 0; n_ < 2; n_++) \
    _Pragma("unroll") for (int k_ = 0; k_ < 2; k_++) \
        acc[m_][(NOFF)+n_] = __builtin_amdgcn_mfma_f32_16x16x32_bf16( \
            AF[m_][k_], BF[n_][k_], acc[m_][(NOFF)+n_], 0, 0, 0); \
    __builtin_amdgcn_s_setprio(0); } while (0)

    f32x4 acc[4][4];
#pragma unroll
    for (int m = 0; m < 4; m++)
#pragma unroll
        for (int n = 0; n < 4; n++) acc[m][n] = (f32x4){0.f, 0.f, 0.f, 0.f};

    const int NT = K >> 6;

    // prologue: tiles 0 (buf0) and 1 (buf1) fully; drain tile0's 6 loads
    STAGE_A(lds, 0, 0); STAGE_B(lds, 0, 0); STAGE_A(lds, 1, 0); STAGE_B(lds, 1, 0);
    STAGE_A(lds + 49152, 0, 1); STAGE_B(lds + 49152, 0, 1);
    STAGE_A(lds + 49152, 1, 1); STAGE_B(lds + 49152, 1, 1);
    asm volatile("s_waitcnt vmcnt(6)" ::: "memory");
    BAR;
    __builtin_amdgcn_sched_barrier(0);

    bf16x8 afA[4][2], bfA[2][2], bfB[2][2];

    for (int t = 0; t < NT; ++t) {
        const char* bc = lds + (t % 3) * 49152;
        char* bs = lds + ((t + 2) % 3) * 49152;
        int ts = t + 2; if (ts >= NT) ts -= NT;
        // wave wr covers A rows [wr*64, wr*64+64): half wr>>1, sub-offset (wr&1)*8192
        const char* Abw = bc + (wr >> 1) * 16384 + (wr & 1) * 8192;
        const char* Bbw = bc + 32768 + wc * 8192;

        // ph1: all A frags + B n0-1
#pragma unroll
        for (int m = 0; m < 4; m++)
#pragma unroll
            for (int kk = 0; kk < 2; kk++)
                afA[m][kk] = *(const bf16x8*)(Abw + m * 2048 + kk * 1024 + abase);
#pragma unroll
        for (int n = 0; n < 2; n++)
#pragma unroll
            for (int kk = 0; kk < 2; kk++)
                bfA[n][kk] = *(const bf16x8*)(Bbw + n * 2048 + kk * 1024 + abase);
        STAGE_A(bs, 0, ts); STAGE_B(bs, 0, ts);
        BAR; DS_FENCE;
        MFMA44(afA, bfA, 0);
        BAR;

        // ph2: B n2-3 (A frags reused)
#pragma unroll
        for (int n = 0; n < 2; n++)
#pragma unroll
            for (int kk = 0; kk < 2; kk++)
                bfB[n][kk] = *(const bf16x8*)(Bbw + (n + 2) * 2048 + kk * 1024 + abase);
        STAGE_A(bs, 1, ts); STAGE_B(bs, 1, ts);
        BAR; DS_FENCE;
        MFMA44(afA, bfB, 2);
        asm volatile("s_waitcnt vmcnt(6)" ::: "memory");
        BAR;
        __builtin_amdgcn_sched_barrier(0);
    }

    asm volatile("s_waitcnt vmcnt(0) lgkmcnt(0)" ::: "memory");

    // epilogue: row = rowBase + wr*64 + m*16 + fq*4 + j; col = colBase + wc*64 + n*16 + fr
    const int crow0 = rowBase + wr * 64 + fq * 4;
    const int ccol0 = colBase + wc * 64 + fr;

#pragma unroll
    for (int n = 0; n < 4; n++) {
        const int col = ccol0 + n * 16;
        if constexpr (EPI == 0) {
            const float bv = bias[col];
            const int seg = col >> 10, scn = col & 1023;
            unsigned short* dst =
                (unsigned short*)(seg == 0 ? out0 : (seg == 1 ? out1 : out2));
#pragma unroll
            for (int m = 0; m < 4; m++) {
                const int r0 = crow0 + m * 16;
#pragma unroll
                for (int j = 0; j < 4; j++)
                    dst[(long long)(r0 + j) * 1024 + scn] = f2bf(acc[m][n][j] + bv);
            }
        } else if constexpr (EPI == 1) {
            unsigned short* dst = (unsigned short*)out0 + (long long)tz * sOz;
#pragma unroll
            for (int m = 0; m < 4; m++) {
                const int r0 = crow0 + m * 16;
#pragma unroll
                for (int j = 0; j < 4; j++)
                    dst[(long long)(r0 + j) * N + col] = f2bf(acc[m][n][j] * scale);
            }
        } else {
            float* dst = (float*)out0;
            const float bv = bias[col];
#pragma unroll
            for (int m = 0; m < 4; m++) {
                const int r0 = crow0 + m * 16;
#pragma unroll
                for (int j = 0; j < 4; j++)
                    dst[(long long)(r0 + j) * N + col] = acc[m][n][j] + bv;
            }
        }
    }
#undef MFMA44
}

// ---------------------------------------------------------------------------
// gemm256: verified 256x256 8-phase kernel — kept for scores (256 blocks = 1.0/CU)
// ---------------------------------------------------------------------------
template<int EPI>
__global__ __launch_bounds__(512, 2) void gemm256(
    const unsigned short* __restrict__ A,
    const unsigned short* __restrict__ Bm,
    int M, int N, int K,
    long long sAz, long long sBz, long long sOz,
    void* __restrict__ out0, void* __restrict__ out1, void* __restrict__ out2,
    const float* __restrict__ bias, float scale)
{
    __shared__ __align__(16) char lds[131072];
    (void)M;

    const unsigned short* Ab = A  + blockIdx.z * sAz;
    const unsigned short* Bb = Bm + blockIdx.z * sBz;
    const int rowBase = blockIdx.y * 256;
    const int colBase = blockIdx.x * 256;
    const int tid = threadIdx.x;
    const int w = tid >> 6, l = tid & 63;
    const int wr = w >> 2, wc = w & 3;
    const int fr = l & 15, fq = l >> 4;

    int sr[2], scl[2];
#pragma unroll
    for (int j = 0; j < 2; j++) {
        int o  = j * 8192 + tid * 16;
        int st = o >> 10;
        int wi = o & 1023;
        wi ^= ((wi >> 9) & 1) << 5;
        sr[j]  = (st >> 1) * 16 + (wi >> 6);
        scl[j] = (st & 1) * 32 + ((wi & 63) >> 1);
    }

    auto STAGE = [&](int buf, int which, int tile) {
        const unsigned short* mat = (which < 2) ? Ab : Bb;
        const int rt0 = ((which < 2) ? rowBase : colBase) + (which & 1) * 128;
        char* dst = lds + buf * 65536 + (which >> 1) * 32768
                        + (which & 1) * 16384 + w * 1024;
        const int k0 = tile * 64;
#pragma unroll
        for (int j = 0; j < 2; j++) {
            const unsigned short* src =
                mat + (long long)(rt0 + sr[j]) * K + k0 + scl[j];
            gload_lds16(src, dst + j * 8192);
        }
    };

    const int abase = (fr * 64 + fq * 16) ^ ((fr & 8) << 2);
    const char* Ah[2] = { lds + wr * 16384, lds + 65536 + wr * 16384 };
    const char* Bh[2] = { lds + 32768 + (wc >> 1) * 16384,
                          lds + 98304 + (wc >> 1) * 16384 };
    const int bn0 = (wc & 1) * 8192;

#define LA(b, m, kk) (*(const bf16x8*)(Ah[b] + (m)*2048 + (kk)*1024 + abase))
#define LB(b, n, kk) (*(const bf16x8*)(Bh[b] + bn0 + (n)*2048 + (kk)*1024 + abase))
#define MFMA16(AF, BF, MOFF, NOFF) do { \
    __builtin_amdgcn_s_setprio(1); \
    _Pragma("unroll") for (int m_ = 0; m_ < 4; m_++) \
    _Pragma("unroll") for (int n_ = 0; n_ < 2; n_++) \
    _Pragma("unroll") for (int k_ = 0; k_ < 2; k_++) \
        acc[(MOFF)+m_][(NOFF)+n_] = __builtin_amdgcn_mfma_f32_16x16x32_bf16( \
            AF[m_][k_], BF[n_][k_], acc[(MOFF)+m_][(NOFF)+n_], 0, 0, 0); \
    __builtin_amdgcn_s_setprio(0); } while (0)

    f32x4 acc[8][4];
#pragma unroll
    for (int m = 0; m < 8; m++)
#pragma unroll
        for (int n = 0; n < 4; n++) acc[m][n] = (f32x4){0.f, 0.f, 0.f, 0.f};

    const int NT = K >> 6;

    STAGE(0, 0, 0); STAGE(0, 1, 0); STAGE(0, 2, 0); STAGE(0, 3, 0);
    STAGE(1, 0, 1); STAGE(1, 1, 1);
    asm volatile("s_waitcnt vmcnt(4)" ::: "memory");
    BAR;
    __builtin_amdgcn_sched_barrier(0);

    bf16x8 afA[4][2], afB[4][2], bfA[2][2], bfB[2][2];

    for (int i = 0; i < NT / 2; i++) {
        const int t1 = 2 * i + 1;
        int t2 = 2 * i + 2; if (t2 >= NT) t2 -= NT;
        int t3 = 2 * i + 3; if (t3 >= NT) t3 -= NT;

#pragma unroll
        for (int m = 0; m < 4; m++) { afA[m][0] = LA(0, m, 0); afA[m][1] = LA(0, m, 1); }
#pragma unroll
        for (int n = 0; n < 2; n++) { bfA[n][0] = LB(0, n, 0); bfA[n][1] = LB(0, n, 1); }
        STAGE(1, 2, t1);
        BAR; DS_FENCE;
        MFMA16(afA, bfA, 0, 0);
        BAR;
#pragma unroll
        for (int m = 0; m < 4; m++) { afB[m][0] = LA(0, 4 + m, 0); afB[m][1] = LA(0, 4 + m, 1); }
        STAGE(1, 3, t1);
        BAR; DS_FENCE;
        MFMA16(afB, bfA, 4, 0);
        BAR;
#pragma unroll
        for (int n = 0; n < 2; n++) { bfB[n][0] = LB(0, 2 + n, 0); bfB[n][1] = LB(0, 2 + n, 1); }
        STAGE(0, 0, t2);
        BAR; DS_FENCE;
        MFMA16(afA, bfB, 0, 2);
        BAR;
        STAGE(0, 1, t2);
        BAR;
        MFMA16(afB, bfB, 4, 2);
        asm volatile("s_waitcnt vmcnt(4)" ::: "memory");
        BAR;
        __builtin_amdgcn_sched_barrier(0);

#pragma unroll
        for (int m = 0; m < 4; m++) { afA[m][0] = LA(1, m, 0); afA[m][1] = LA(1, m, 1); }
#pragma unroll
        for (int n = 0; n < 2; n++) { bfA[n][0] = LB(1, n, 0); bfA[n][1] = LB(1, n, 1); }
        STAGE(0, 2, t2);
        BAR; DS_FENCE;
        MFMA16(afA, bfA, 0, 0);
        BAR;
#pragma unroll
        for (int m = 0; m < 4; m++) { afB[m][0] = LA(1, 4 + m, 0); afB[m][1] = LA(1, 4 + m, 1); }
        STAGE(0, 3, t2);
        BAR; DS_FENCE;
        MFMA16(afB, bfA, 4, 0);
        BAR;
#pragma unroll
        for (int n = 0; n < 2; n++) { bfB[n][0] = LB(1, 2 + n, 0); bfB[n][1] = LB(1, 2 + n, 1); }
        STAGE(1, 0, t3);
        BAR; DS_FENCE;
        MFMA16(afA, bfB, 0, 2);
        BAR;
        STAGE(1, 1, t3);
        BAR;
        MFMA16(afB, bfB, 4, 2);
        asm volatile("s_waitcnt vmcnt(4)" ::: "memory");
        BAR;
        __builtin_amdgcn_sched_barrier(0);
    }

    asm volatile("s_waitcnt vmcnt(0) lgkmcnt(0)" ::: "memory");

    const int crow0 = rowBase + wr * 128 + fq * 4;
    const int ccol0 = colBase + wc * 64 + fr;

#pragma unroll
    for (int n = 0; n < 4; n++) {
        const int col = ccol0 + n * 16;
        if constexpr (EPI == 1) {
            unsigned short* dst = (unsigned short*)out0 + blockIdx.z * sOz;
#pragma unroll
            for (int m = 0; m < 8; m++) {
                const int r0 = crow0 + m * 16;
#pragma unroll
                for (int j = 0; j < 4; j++)
                    dst[(long long)(r0 + j) * N + col] = f2bf(acc[m][n][j] * scale);
            }
        }
    }
    (void)out1; (void)out2; (void)bias;
#undef LA
#undef LB
#undef MFMA16
}

// f32 -> bf16 elementwise (8/thread, vectorized)
__global__ __launch_bounds__(256) void conv_f32_bf16(
    const float* __restrict__ in, unsigned short* __restrict__ out, int n8)
{
    for (int i = blockIdx.x * blockDim.x + threadIdx.x; i < n8;
         i += gridDim.x * blockDim.x) {
        const float4 a = ((const float4*)in)[2 * i];
        const float4 b = ((const float4*)in)[2 * i + 1];
        u16x8 o;
        o[0] = f2bf(a.x); o[1] = f2bf(a.y); o[2] = f2bf(a.z); o[3] = f2bf(a.w);
        o[4] = f2bf(b.x); o[5] = f2bf(b.y); o[6] = f2bf(b.z); o[7] = f2bf(b.w);
        ((u16x8*)out)[i] = o;
    }
}

// out[cols][rows] (bf16) = transpose(in[rows][cols] f32)
__global__ __launch_bounds__(256) void tconv_f32_bf16(
    const float* __restrict__ in, unsigned short* __restrict__ out,
    int rows, int cols)
{
    __shared__ float t[32][33];
    const int c0 = blockIdx.x * 32, r0 = blockIdx.y * 32;
    const int tx = threadIdx.x & 31, ty = threadIdx.x >> 5;
#pragma unroll
    for (int i = 0; i < 4; i++)
        t[ty + 8 * i][tx] = in[(long long)(r0 + ty + 8 * i) * cols + c0 + tx];
    __syncthreads();
#pragma unroll
    for (int i = 0; i < 4; i++)
        out[(long long)(c0 + ty + 8 * i) * rows + r0 + tx] = f2bf(t[tx][ty + 8 * i]);
}

// bf16 transpose, batched via grid.z
__global__ __launch_bounds__(256) void t_bf16(
    const unsigned short* __restrict__ in, unsigned short* __restrict__ out,
    int rows, int cols, long long sIz, long long sOz)
{
    __shared__ unsigned short t[32][33];
    in  += blockIdx.z * sIz;
    out += blockIdx.z * sOz;
    const int c0 = blockIdx.x * 32, r0 = blockIdx.y * 32;
    const int tx = threadIdx.x & 31, ty = threadIdx.x >> 5;
#pragma unroll
    for (int i = 0; i < 4; i++)
        t[ty + 8 * i][tx] = in[(long long)(r0 + ty + 8 * i) * cols + c0 + tx];
    __syncthreads();
#pragma unroll
    for (int i = 0; i < 4; i++)
        out[(long long)(c0 + ty + 8 * i) * rows + r0 + tx] = t[tx][ty + 8 * i];
}

// in-place row softmax over S_=2048 bf16 logits; one block (256 thr) per row
__global__ __launch_bounds__(256) void softmax_rows(unsigned short* __restrict__ sc)
{
    const long long row = blockIdx.x;
    unsigned short* p = sc + row * S_;
    const int tid = threadIdx.x, w = tid >> 6, l = tid & 63;

    u16x8 v = *reinterpret_cast<const u16x8*>(&p[tid * 8]);
    float f[8];
#pragma unroll
    for (int i = 0; i < 8; i++) f[i] = bf2f(v[i]);

    float m = f[0];
#pragma unroll
    for (int i = 1; i < 8; i++) m = fmaxf(m, f[i]);
    for (int o = 32; o; o >>= 1) m = fmaxf(m, __shfl_xor(m, o));
    __shared__ float red[8];
    if (l == 0) red[w] = m;
    __syncthreads();
    m = fmaxf(fmaxf(red[0], red[1]), fmaxf(red[2], red[3]));

    float s = 0.f;
#pragma unroll
    for (int i = 0; i < 8; i++) { f[i] = __expf(f[i] - m); s += f[i]; }
    for (int o = 32; o; o >>= 1) s += __shfl_xor(s, o);
    if (l == 0) red[4 + w] = s;
    __syncthreads();
    s = red[4] + red[5] + red[6] + red[7];

    const float inv = 1.0f / s;
    u16x8 o8;
#pragma unroll
    for (int i = 0; i < 8; i++) o8[i] = f2bf(f[i] * inv);
    *reinterpret_cast<u16x8*>(&p[tid * 8]) = o8;
}

extern "C" void kernel_launch(void* const* d_in, const int* in_sizes, int n_in,
                              void* d_out, int out_size, void* d_ws, size_t ws_size,
                              hipStream_t stream)
{
    (void)in_sizes; (void)n_in; (void)out_size; (void)ws_size;
    const float* x  = (const float*)d_in[0];
    const float* W1 = (const float*)d_in[1];
    const float* b1 = (const float*)d_in[2];
    const float* W2 = (const float*)d_in[3];
    const float* b2 = (const float*)d_in[4];
    float* out = (float*)d_out;

    char* ws = (char*)d_ws;
    size_t off = 0;
    auto alloc = [&](size_t bytes) {
        void* p = ws + off;
        off += (bytes + 255) & ~(size_t)255;
        return p;
    };
    unsigned short* xbf = (unsigned short*)alloc((size_t)BS_ * D_ * 2);
    unsigned short* w1t = (unsigned short*)alloc((size_t)N3H * D_ * 2);
    unsigned short* w2t = (unsigned short*)alloc((size_t)H_ * H_ * 2);
    unsigned short* q   = (unsigned short*)alloc((size_t)BS_ * H_ * 2);
    unsigned short* k   = (unsigned short*)alloc((size_t)BS_ * H_ * 2);
    unsigned short* v   = (unsigned short*)alloc((size_t)BS_ * H_ * 2);
    unsigned short* vt  = (unsigned short*)alloc((size_t)BS_ * H_ * 2);
    unsigned short* sc  = (unsigned short*)alloc((size_t)B_ * S_ * S_ * 2);
    unsigned short* ctx = v;  // alias: v is dead after transpose, before PV writes

    const float scale = 0.022097086912079608f;  // (2*D)^-0.5 = 1/sqrt(2048)

    conv_f32_bf16<<<dim3(2048), dim3(256), 0, stream>>>(x, xbf, BS_ * D_ / 8);
    tconv_f32_bf16<<<dim3(N3H / 32, D_ / 32), dim3(256), 0, stream>>>(W1, w1t, D_, N3H);
    tconv_f32_bf16<<<dim3(H_ / 32, H_ / 32), dim3(256), 0, stream>>>(W2, w2t, H_, H_);

    // QKV: [8192,3072] = xbf @ w1t^T, split q/k/v, +b1.  24x32 = 768 tiles = 3.0/CU
    gemm128<0><<<dim3(768), dim3(512), 0, stream>>>(
        xbf, w1t, 24, 32, N3H, D_, 0LL, 0LL, 0LL, q, k, v, b1, 1.0f);

    // vt[b][h][s] = v[b][s][h]
    t_bf16<<<dim3(H_ / 32, S_ / 32, B_), dim3(256), 0, stream>>>(
        v, vt, S_, H_, (long long)S_ * H_, (long long)S_ * H_);

    // scores[b] = (q[b] @ k[b]^T) * scale  [2048,2048] bf16 — 256 blocks = 1.0/CU
    gemm256<1><<<dim3(S_ / 256, S_ / 256, B_), dim3(512), 0, stream>>>(
        q, k, S_, S_, H_, (long long)S_ * H_, (long long)S_ * H_, (long long)S_ * S_,
        sc, nullptr, nullptr, nullptr, scale);

    softmax_rows<<<dim3(BS_), dim3(256), 0, stream>>>(sc);

    // ctx[b] = P[b] @ vt[b]^T  [2048,1024] bf16.  8x8x4 = 256 tiles = 1.0/CU
    gemm128<1><<<dim3(256), dim3(512), 0, stream>>>(
        sc, vt, 8, 8, H_, S_, (long long)S_ * S_, (long long)H_ * S_,
        (long long)S_ * H_, ctx, nullptr, nullptr, nullptr, 1.0f);

    // out = ctx @ w2t^T + b2  [8192,1024] f32.  8x32 = 256 tiles = 1.0/CU
    gemm128<3><<<dim3(256), dim3(512), 0, stream>>>(
        ctx, w2t, 8, 32, H_, H_, 0LL, 0LL, 0LL, out, nullptr, nullptr, b2, 1.0f);
}